// Round 2
// baseline (271.537 us; speedup 1.0000x reference)
//
#include <hip/hip_runtime.h>
#include <math.h>

#define NT      32768
#define DIM     2048
#define NE      64
#define RSCALE  2.5f
#define REPS    1e-20f
#define BK      64
#define TOK     64

typedef const __attribute__((address_space(1))) void GV;
typedef __attribute__((address_space(3))) void LV;

#define FMA4(S, HV, WV) \
    S = fmaf((HV).x, (WV).x, S); \
    S = fmaf((HV).y, (WV).y, S); \
    S = fmaf((HV).z, (WV).z, S); \
    S = fmaf((HV).w, (WV).w, S);

// 512 blocks x 512 threads (8 waves). Block = 64 tokens, wave w = experts w*8..w*8+7,
// lane = token. W read via uniform (scalar) loads; H staged to LDS via global_load_lds
// with XOR-swizzled global source (LDS stays linear).
__global__ __launch_bounds__(512) void router_kernel(
    const float* __restrict__ H,
    const float* __restrict__ W,
    const float* __restrict__ B,
    float* __restrict__ out)
{
    __shared__ __align__(16) float Hs[TOK * BK];   // 16 KB, swizzled slots
    __shared__ float Sc[TOK][NE + 1];              // scores, padded pitch
    __shared__ float Bs[NE];

    const int tid  = threadIdx.x;
    const int lane = tid & 63;
    const int wave = __builtin_amdgcn_readfirstlane(tid >> 6);
    const size_t tb = (size_t)blockIdx.x * TOK;

    if (tid < NE) Bs[tid] = B[tid];

    // --- staging addresses: wave stages rows wave*8 .. wave*8+7 in 2 rounds of 4 rows.
    // LDS dest is linear (base + lane*16B): lane -> (row = base_row + lane>>4, slot_phys = lane&15).
    // Stored content must satisfy Hs[row][slot_phys] = H_row[ k0 + 4*(slot_phys ^ (row&7)) .. +3 ]
    // so we pre-swizzle the global source address per lane.
    const int sp    = lane & 15;
    const int srow0 = wave * 8 + (lane >> 4);
    const int srow1 = srow0 + 4;
    const float* g0 = H + (tb + (size_t)srow0) * DIM + ((sp ^ (srow0 & 7)) << 2);
    const float* g1 = H + (tb + (size_t)srow1) * DIM + ((sp ^ (srow1 & 7)) << 2);
    float* l0 = &Hs[(wave * 8) * BK];
    float* l1 = &Hs[(wave * 8 + 4) * BK];

    const int we = wave * 8;                        // expert base (uniform -> scalar W loads)
    const float* wbase = W + (size_t)we * DIM;

    float  c[8];
    double acc[8];
    #pragma unroll
    for (int j = 0; j < 8; ++j) { c[j] = 0.0f; acc[j] = 0.0; }

    for (int k0 = 0; k0 < DIM; k0 += BK) {
        __syncthreads();   // prev chunk fully consumed before overwrite
        __builtin_amdgcn_global_load_lds((GV*)(g0 + k0), (LV*)l0, 16, 0, 0);
        __builtin_amdgcn_global_load_lds((GV*)(g1 + k0), (LV*)l1, 16, 0, 0);
        __syncthreads();   // compiler drains vmcnt before barrier -> Hs ready

        #pragma unroll
        for (int k16 = 0; k16 < 4; ++k16) {
            // h fragment: 4 k-values per read, row = lane, XOR-swizzled slot (conflict-free)
            float4 hv[4];
            #pragma unroll
            for (int i = 0; i < 4; ++i) {
                const int s = k16 * 4 + i;
                hv[i] = *(const float4*)&Hs[lane * BK + ((s ^ (lane & 7)) << 2)];
            }
            #pragma unroll
            for (int eg = 0; eg < 2; ++eg) {
                float4 wv[4][4];
                #pragma unroll
                for (int e = 0; e < 4; ++e) {
                    const float4* wp = (const float4*)(wbase + (size_t)(eg * 4 + e) * DIM
                                                       + k0 + k16 * 16);
                    wv[e][0] = wp[0]; wv[e][1] = wp[1]; wv[e][2] = wp[2]; wv[e][3] = wp[3];
                }
                #pragma unroll
                for (int e = 0; e < 4; ++e) {
                    float s0 = c[eg * 4 + e];
                    FMA4(s0, hv[0], wv[e][0]);
                    FMA4(s0, hv[1], wv[e][1]);
                    FMA4(s0, hv[2], wv[e][2]);
                    FMA4(s0, hv[3], wv[e][3]);
                    c[eg * 4 + e] = s0;
                }
            }
            // flush 16-dim fp32 subchunk into fp64 master (rank-exactness vs np reference)
            #pragma unroll
            for (int j = 0; j < 8; ++j) { acc[j] += (double)c[j]; c[j] = 0.0f; }
        }
    }

    // sigmoid scores into LDS: token = lane, experts we..we+7
    #pragma unroll
    for (int j = 0; j < 8; ++j) {
        float logit = (float)acc[j];
        Sc[lane][we + j] = 1.0f / (1.0f + expf(-logit));
    }
    __syncthreads();

    // grouped top-k, one token per active thread, spread across all 8 waves
    if ((tid & 7) == 0) {
        const int t = tid >> 3;                    // 0..63
        const float* sc = Sc[t];
        float gs[8];
        #pragma unroll
        for (int g = 0; g < 8; ++g) {
            float m1 = -1e30f, m2 = -1e30f;
            #pragma unroll
            for (int j = 0; j < 8; ++j) {
                float v = sc[g * 8 + j] + Bs[g * 8 + j];
                if (v > m1) { m2 = m1; m1 = v; }
                else if (v > m2) { m2 = v; }
            }
            gs[g] = m1 + m2;
        }
        unsigned gmask = 0;
        for (int i = 0; i < 4; ++i) {
            float best = -1e30f; int bg = 0;
            for (int g = 0; g < 8; ++g)
                if (!((gmask >> g) & 1u) && gs[g] > best) { best = gs[g]; bg = g; }
            gmask |= 1u << bg;
        }
        unsigned long long picked = 0ull;
        int   idxs[8];
        float wts[8];
        float wsum = 0.0f;
        for (int i = 0; i < 8; ++i) {
            float best = -1e30f; int bi = 0;
            for (int e = 0; e < 64; ++e) {
                if ((picked >> e) & 1ull) continue;
                float v = ((gmask >> (e >> 3)) & 1u) ? (sc[e] + Bs[e]) : 0.0f;
                if (v > best) { best = v; bi = e; }
            }
            picked |= 1ull << bi;
            idxs[i] = bi;
            wts[i] = sc[bi];
            wsum += sc[bi];
        }
        const float scale = RSCALE / (wsum + REPS);
        const size_t token = tb + t;
        #pragma unroll
        for (int i = 0; i < 8; ++i) {
            out[token * 8 + i] = (float)idxs[i];
            out[(size_t)NT * 8 + token * 8 + i] = wts[i] * scale;
        }
    }
}

extern "C" void kernel_launch(void* const* d_in, const int* in_sizes, int n_in,
                              void* d_out, int out_size, void* d_ws, size_t ws_size,
                              hipStream_t stream) {
    (void)in_sizes; (void)n_in; (void)out_size; (void)d_ws; (void)ws_size;
    const float* H = (const float*)d_in[0];
    const float* W = (const float*)d_in[1];
    const float* B = (const float*)d_in[2];
    float* out = (float*)d_out;
    router_kernel<<<dim3(NT / TOK), dim3(512), 0, stream>>>(H, W, B, out);
}

// Round 3
// 250.865 us; speedup vs baseline: 1.0824x; 1.0824x over previous
//
#include <hip/hip_runtime.h>
#include <math.h>

#define NT      32768
#define DIM     2048
#define NE      64
#define RSCALE  2.5f
#define REPS    1e-20f
#define BK      64
#define TOK     64
#define NCHUNK  (DIM / BK)

typedef const __attribute__((address_space(1))) void GV;
typedef __attribute__((address_space(3))) void LV;

#define FMA4(S, HV, WV) \
    S = fmaf((HV).x, (WV).x, S); \
    S = fmaf((HV).y, (WV).y, S); \
    S = fmaf((HV).z, (WV).z, S); \
    S = fmaf((HV).w, (WV).w, S);

// 512 blocks x 512 threads (8 waves). Block = 64 tokens, wave w = experts w*8..w*8+7,
// lane = token. W via uniform scalar loads (SGPR operands); H double-buffered in LDS,
// staged with global_load_lds (XOR-pre-swizzled global source, linear LDS dest).
// 2-phase pipeline: stage(next) -> compute(cur) -> one barrier per chunk.
__global__ __launch_bounds__(512) void router_kernel(
    const float* __restrict__ H,
    const float* __restrict__ W,
    const float* __restrict__ B,
    float* __restrict__ out)
{
    __shared__ __align__(16) float Hs[2][TOK * BK];  // 2 x 16 KB, swizzled slots
    __shared__ float Sc[TOK][NE + 1];                // scores, padded pitch
    __shared__ float Bs[NE];

    const int tid  = threadIdx.x;
    const int lane = tid & 63;
    const int wave = __builtin_amdgcn_readfirstlane(tid >> 6);
    const size_t tb = (size_t)blockIdx.x * TOK;

    if (tid < NE) Bs[tid] = B[tid];

    // staging: wave stages rows wave*8 .. wave*8+7 in 2 rounds of 4 rows.
    // LDS dest linear (base + lane*16B): lane -> (row = base + lane>>4, slot_phys = lane&15).
    // Content: Hs[row][slot] = H_row[k0 + 4*(slot ^ (row&7)) ..] -> pre-swizzle global source.
    const int sp    = lane & 15;
    const int srow0 = wave * 8 + (lane >> 4);
    const int srow1 = srow0 + 4;
    const float* g0 = H + (tb + (size_t)srow0) * DIM + ((sp ^ (srow0 & 7)) << 2);
    const float* g1 = H + (tb + (size_t)srow1) * DIM + ((sp ^ (srow1 & 7)) << 2);
    const int lo0 = (wave * 8) * BK;
    const int lo1 = (wave * 8 + 4) * BK;

    const int we = wave * 8;                         // expert base (uniform)
    const float* wbase = W + (size_t)we * DIM;

    float  c[8];
    double acc[8];
    #pragma unroll
    for (int j = 0; j < 8; ++j) { c[j] = 0.0f; acc[j] = 0.0; }

    // prologue: stage chunk 0 into buffer 0
    __builtin_amdgcn_global_load_lds((GV*)g0, (LV*)&Hs[0][lo0], 16, 0, 0);
    __builtin_amdgcn_global_load_lds((GV*)g1, (LV*)&Hs[0][lo1], 16, 0, 0);
    __syncthreads();

    for (int ch = 0; ch < NCHUNK; ++ch) {
        const int cur = ch & 1;
        const int k0  = ch * BK;

        // stage NEXT chunk first -- its latency hides under this chunk's compute
        if (ch + 1 < NCHUNK) {
            const int kn = k0 + BK;
            __builtin_amdgcn_global_load_lds((GV*)(g0 + kn), (LV*)&Hs[cur ^ 1][lo0], 16, 0, 0);
            __builtin_amdgcn_global_load_lds((GV*)(g1 + kn), (LV*)&Hs[cur ^ 1][lo1], 16, 0, 0);
        }

        const float* hrow = &Hs[cur][lane * BK];
        #pragma unroll
        for (int k16 = 0; k16 < 4; ++k16) {
            float4 hv[4];
            #pragma unroll
            for (int i = 0; i < 4; ++i) {
                const int s = k16 * 4 + i;
                hv[i] = *(const float4*)&hrow[(s ^ (lane & 7)) << 2];
            }
            #pragma unroll
            for (int eg = 0; eg < 2; ++eg) {
                float4 wv[4][4];
                #pragma unroll
                for (int e = 0; e < 4; ++e) {
                    const float4* wp = (const float4*)(wbase + (size_t)(eg * 4 + e) * DIM
                                                       + k0 + k16 * 16);
                    wv[e][0] = wp[0]; wv[e][1] = wp[1]; wv[e][2] = wp[2]; wv[e][3] = wp[3];
                }
                #pragma unroll
                for (int e = 0; e < 4; ++e) {
                    float s0 = c[eg * 4 + e];
                    FMA4(s0, hv[0], wv[e][0]);
                    FMA4(s0, hv[1], wv[e][1]);
                    FMA4(s0, hv[2], wv[e][2]);
                    FMA4(s0, hv[3], wv[e][3]);
                    c[eg * 4 + e] = s0;
                }
            }
            // flush 16-dim fp32 subchunk into fp64 master (rank-exactness vs np reference)
            #pragma unroll
            for (int j = 0; j < 8; ++j) { acc[j] += (double)c[j]; c[j] = 0.0f; }
        }
        __syncthreads();   // next buffer ready (vmcnt drained); cur free for overwrite
    }

    // sigmoid scores into LDS: token = lane, experts we..we+7
    #pragma unroll
    for (int j = 0; j < 8; ++j) {
        float logit = (float)acc[j];
        Sc[lane][we + j] = 1.0f / (1.0f + expf(-logit));
    }
    __syncthreads();

    // grouped top-k, one token per active thread, spread across all 8 waves
    if ((tid & 7) == 0) {
        const int t = tid >> 3;                    // 0..63
        const float* sc = Sc[t];
        float gs[8];
        #pragma unroll
        for (int g = 0; g < 8; ++g) {
            float m1 = -1e30f, m2 = -1e30f;
            #pragma unroll
            for (int j = 0; j < 8; ++j) {
                float v = sc[g * 8 + j] + Bs[g * 8 + j];
                if (v > m1) { m2 = m1; m1 = v; }
                else if (v > m2) { m2 = v; }
            }
            gs[g] = m1 + m2;
        }
        unsigned gmask = 0;
        for (int i = 0; i < 4; ++i) {
            float best = -1e30f; int bg = 0;
            for (int g = 0; g < 8; ++g)
                if (!((gmask >> g) & 1u) && gs[g] > best) { best = gs[g]; bg = g; }
            gmask |= 1u << bg;
        }
        unsigned long long picked = 0ull;
        int   idxs[8];
        float wts[8];
        float wsum = 0.0f;
        for (int i = 0; i < 8; ++i) {
            float best = -1e30f; int bi = 0;
            for (int e = 0; e < 64; ++e) {
                if ((picked >> e) & 1ull) continue;
                float v = ((gmask >> (e >> 3)) & 1u) ? (sc[e] + Bs[e]) : 0.0f;
                if (v > best) { best = v; bi = e; }
            }
            picked |= 1ull << bi;
            idxs[i] = bi;
            wts[i] = sc[bi];
            wsum += sc[bi];
        }
        const float scale = RSCALE / (wsum + REPS);
        const size_t token = tb + t;
        #pragma unroll
        for (int i = 0; i < 8; ++i) {
            out[token * 8 + i] = (float)idxs[i];
            out[(size_t)NT * 8 + token * 8 + i] = wts[i] * scale;
        }
    }
}

extern "C" void kernel_launch(void* const* d_in, const int* in_sizes, int n_in,
                              void* d_out, int out_size, void* d_ws, size_t ws_size,
                              hipStream_t stream) {
    (void)in_sizes; (void)n_in; (void)out_size; (void)d_ws; (void)ws_size;
    const float* H = (const float*)d_in[0];
    const float* W = (const float*)d_in[1];
    const float* B = (const float*)d_in[2];
    float* out = (float*)d_out;
    router_kernel<<<dim3(NT / TOK), dim3(512), 0, stream>>>(H, W, B, out);
}